// Round 9
// baseline (817.276 us; speedup 1.0000x reference)
//
#include <hip/hip_runtime.h>
#include <hip/hip_bf16.h>
#include <math.h>

using bf16 = __hip_bfloat16;

__device__ __forceinline__ float bf2f(bf16 v) { return __bfloat162float(v); }
__device__ __forceinline__ bf16  f2bf(float v) { return __float2bfloat16(v); }

#define HW_ 4096  // H*W = 64*64

// Module-scope scratch for prompt K (normalized) / V; recomputed every call.
__device__ float g_pn[100 * 64];
__device__ float g_pv[100 * 64];

// ---------------- kernel 1: prompt K (normalized) and V ----------------
__global__ __launch_bounds__(256) void k_prompt(
    const float* __restrict__ prompts,
    const float* __restrict__ pkw, const float* __restrict__ pkb,
    const float* __restrict__ pvw, const float* __restrict__ pvb)
{
  __shared__ float pk[100][64];
  int t = threadIdx.x;
  for (int idx = t; idx < 6400; idx += 256) {
    int k = idx >> 6, j = idx & 63;
    float a = pkb[j], v = pvb[j];
    const float* pr = prompts + k * 64;
    for (int p = 0; p < 64; ++p) {
      float pf = pr[p];
      a += pf * pkw[j * 64 + p];
      v += pf * pvw[j * 64 + p];
    }
    pk[k][j] = a;
    g_pv[k * 64 + j] = v;
  }
  __syncthreads();
  for (int k = t; k < 100; k += 256) {
    float s = 0.f;
    for (int j = 0; j < 64; ++j) s += pk[k][j] * pk[k][j];
    float inv = 1.f / fmaxf(sqrtf(s), 1e-12f);
    for (int j = 0; j < 64; ++j) g_pn[k * 64 + j] = pk[k][j] * inv;
  }
}

// ---------------- kernel 2: fused main, 32 positions/block ----------------
// grid: B*H*2 = 1024 blocks, 256 threads = 8 groups x 32 lanes.
// Inputs f32; OUTPUTS f32 (reference output dtype).
__global__ __launch_bounds__(256) void k_main(
    const float* __restrict__ x,  const float* __restrict__ ir,
    const float* __restrict__ dww, const float* __restrict__ dwb,
    const float* __restrict__ pww, const float* __restrict__ pwb,
    const float* __restrict__ lnw, const float* __restrict__ lnb,
    const float* __restrict__ tdw, const float* __restrict__ tdb,
    const float* __restrict__ qw,  const float* __restrict__ qb,
    const float* __restrict__ projw, const float* __restrict__ projb,
    const float* __restrict__ temp,
    float* __restrict__ out, float* __restrict__ unc)
{
  __shared__ bf16  st[192][32];
  __shared__ bf16  gam[64][32];
  __shared__ bf16  bet[64][32];
  __shared__ bf16  xch[64][32];
  __shared__ bf16  tdch[64][64];
  __shared__ float xt[32][65];
  __shared__ float qt[32][65];
  __shared__ float att[32][100];
  __shared__ float redA[8][32];
  __shared__ float redB[8][32];
  __shared__ float muS[32], invS[32], invqS[32], msS[32], denS[32], uuS[32];

  int bid = blockIdx.x;
  int b = bid >> 7;
  int rem = bid & 127;
  int h = rem >> 1;
  int w0 = (rem & 1) * 32;
  int t = threadIdx.x, w = t & 31, g = t >> 5;
  const float* xrow = x + (size_t)b * 512 * HW_ + h * 64 + w0;

  // ---- style head: dw 3x3 + SiLU ----
  for (int c = g; c < 192; c += 8) {
    float acc = dwb[c];
    const float* irc = ir + ((size_t)b * 192 + c) * HW_;
#pragma unroll
    for (int ky = 0; ky < 3; ++ky) {
      int hh = h + ky - 1;
      if (hh < 0 || hh >= 64) continue;
#pragma unroll
      for (int kx = 0; kx < 3; ++kx) {
        int ww = w0 + w + kx - 1;
        if (ww < 0 || ww >= 64) continue;
        acc += irc[hh * 64 + ww] * dww[c * 9 + ky * 3 + kx];
      }
    }
    st[c][w] = f2bf(acc / (1.f + __expf(-acc)));
  }
  __syncthreads();

  // ---- pw 1x1 -> gamma, beta ----
  for (int j = g; j < 128; j += 8) {
    float acc = pwb[j];
    const float* pr = pww + j * 192;
    for (int c = 0; c < 192; ++c) acc += bf2f(st[c][w]) * pr[c];
    if (j < 64) gam[j][w]      = f2bf(acc);
    else        bet[j - 64][w] = f2bf(acc);
  }
  __syncthreads();

  // ---- LN stats ----
  float s1 = 0.f, s2 = 0.f;
  for (int c = g; c < 512; c += 8) {
    float v = xrow[c * HW_ + w];
    s1 += v; s2 += v * v;
  }
  redA[g][w] = s1; redB[g][w] = s2;
  __syncthreads();
  if (t < 32) {
    float sa = 0.f, sb = 0.f;
    for (int gg = 0; gg < 8; ++gg) { sa += redA[gg][t]; sb += redB[gg][t]; }
    float m = sa * (1.f / 512.f);
    muS[t] = m;
    invS[t] = rsqrtf(sb * (1.f / 512.f) - m * m + 1e-6f);
  }
  __syncthreads();
  float mu = muS[w], inv = invS[w];

  // ---- td matmul (512 -> 64), chunked ----
  float acc[8];
#pragma unroll
  for (int i = 0; i < 8; ++i) acc[i] = tdb[g * 8 + i];

  for (int ch = 0; ch < 8; ++ch) {
    int c0 = ch * 64;
#pragma unroll
    for (int i = 0; i < 8; ++i) {
      int r = g + i * 8;
      xch[r][w] = f2bf(xrow[(c0 + r) * HW_ + w]);
    }
    for (int idx = t; idx < 4096; idx += 256)
      tdch[idx >> 6][idx & 63] = f2bf(tdw[(idx >> 6) * 512 + c0 + (idx & 63)]);
    __syncthreads();
    for (int cc = 0; cc < 64; ++cc) {
      int c = c0 + cc;
      float xn = (bf2f(xch[cc][w]) - mu) * inv * lnw[c] + lnb[c];
#pragma unroll
      for (int i = 0; i < 8; ++i) acc[i] += xn * bf2f(tdch[g * 8 + i][cc]);
    }
    __syncthreads();
  }

  // ---- FiLM ----
#pragma unroll
  for (int i = 0; i < 8; ++i) {
    int j = g * 8 + i;
    xt[w][j] = acc[i] * (1.f + bf2f(gam[j][w])) + bf2f(bet[j][w]);
  }
  __syncthreads();

  // ---- q ----
  float qa[8];
#pragma unroll
  for (int i = 0; i < 8; ++i) qa[i] = qb[g * 8 + i];
  for (int j = 0; j < 64; ++j) {
    float xv = xt[w][j];
#pragma unroll
    for (int i = 0; i < 8; ++i) qa[i] += xv * qw[(g * 8 + i) * 64 + j];
  }
  float ss = 0.f;
#pragma unroll
  for (int i = 0; i < 8; ++i) { qt[w][g * 8 + i] = qa[i]; ss += qa[i] * qa[i]; }
  redA[g][w] = ss;
  __syncthreads();
  if (t < 32) {
    float s = 0.f;
    for (int gg = 0; gg < 8; ++gg) s += redA[gg][t];
    invqS[t] = 1.f / fmaxf(sqrtf(s), 1e-12f);
  }
  __syncthreads();

  // ---- cos_sim + running max ----
  float iq = invqS[w];
  float lmax = -1e30f;
  for (int k = g; k < 100; k += 8) {
    float s = 0.f;
    const float* pnk = g_pn + k * 64;
    for (int j = 0; j < 64; ++j) s += qt[w][j] * pnk[j];
    s *= iq;
    att[w][k] = s;
    lmax = fmaxf(lmax, s);
  }
  redA[g][w] = lmax;
  __syncthreads();
  if (t < 32) {
    float m = -1e30f;
    for (int gg = 0; gg < 8; ++gg) m = fmaxf(m, redA[gg][t]);
    msS[t] = m;
    float u = 1.f - (m + 1.f) * 0.5f;
    uuS[t] = u;
    unc[(size_t)b * HW_ + h * 64 + w0 + t] = u;   // f32 store
  }
  __syncthreads();

  // ---- softmax numerators ----
  float m = msS[w];
  float invT = 1.f / temp[0];
  float lsum = 0.f;
  for (int k = g; k < 100; k += 8) {
    float e = __expf((att[w][k] - m) * invT);
    att[w][k] = e;
    lsum += e;
  }
  redB[g][w] = lsum;
  __syncthreads();
  if (t < 32) {
    float s = 0.f;
    for (int gg = 0; gg < 8; ++gg) s += redB[gg][t];
    denS[t] = s;
  }
  __syncthreads();

  // ---- proto + calibrate ----
  float pr[8];
#pragma unroll
  for (int i = 0; i < 8; ++i) pr[i] = 0.f;
  for (int k = 0; k < 100; ++k) {
    float a = att[w][k];
    const float* pvk = g_pv + k * 64 + g * 8;
#pragma unroll
    for (int i = 0; i < 8; ++i) pr[i] += a * pvk[i];
  }
  float u = uuS[w];
  float dinv = u / denS[w];
  float om = 1.f - u;
#pragma unroll
  for (int i = 0; i < 8; ++i) {
    int j = g * 8 + i;
    xt[w][j] = om * xt[w][j] + dinv * pr[i];
  }
  __syncthreads();

  // ---- proj (64 -> 512) + residual ----
  float xc[64];
#pragma unroll
  for (int j = 0; j < 64; ++j) xc[j] = xt[w][j];

  for (int c = g; c < 512; c += 8) {
    float a = projb[c];
    const float4* prow = (const float4*)(projw + c * 64);
#pragma unroll
    for (int v4 = 0; v4 < 16; ++v4) {
      float4 p = prow[v4];
      a += xc[v4 * 4 + 0] * p.x + xc[v4 * 4 + 1] * p.y
         + xc[v4 * 4 + 2] * p.z + xc[v4 * 4 + 3] * p.w;
    }
    a += xrow[c * HW_ + w];
    out[(size_t)b * 512 * HW_ + c * HW_ + h * 64 + w0 + w] = a;   // f32 store
  }
}

extern "C" void kernel_launch(void* const* d_in, const int* in_sizes, int n_in,
                              void* d_out, int out_size, void* d_ws, size_t ws_size,
                              hipStream_t stream) {
  const float* x     = (const float*)d_in[0];
  const float* ir    = (const float*)d_in[1];
  const float* dww   = (const float*)d_in[2];
  const float* dwb   = (const float*)d_in[3];
  const float* pww   = (const float*)d_in[4];
  const float* pwb   = (const float*)d_in[5];
  const float* lnw   = (const float*)d_in[6];
  const float* lnb   = (const float*)d_in[7];
  const float* tdw   = (const float*)d_in[8];
  const float* tdb   = (const float*)d_in[9];
  const float* qw    = (const float*)d_in[10];
  const float* qb    = (const float*)d_in[11];
  const float* pkw   = (const float*)d_in[12];
  const float* pkb   = (const float*)d_in[13];
  const float* pvw   = (const float*)d_in[14];
  const float* pvb   = (const float*)d_in[15];
  const float* prompts = (const float*)d_in[16];
  const float* projw = (const float*)d_in[17];
  const float* projb = (const float*)d_in[18];
  const float* temp  = (const float*)d_in[19];

  float* outp = (float*)d_out;                 // (B,512,64,64) f32
  float* uncp = outp + (size_t)8 * 512 * HW_;  // (B,1,64,64)  f32

  (void)d_ws; (void)ws_size;  // no workspace use

  k_prompt<<<1, 256, 0, stream>>>(prompts, pkw, pkb, pvw, pvb);
  k_main<<<1024, 256, 0, stream>>>(x, ir, dww, dwb, pww, pwb, lnw, lnb,
                                   tdw, tdb, qw, qb,
                                   projw, projb, temp, outp, uncp);
}